// Round 4
// baseline (29.546 us; speedup 1.0000x reference)
//
#include <hip/hip_runtime.h>
#include <hip/hip_bf16.h>

// HungarianMatcher cost matrix:
//   C[i, j] = 10 * L1(pred_pts[i], gt_pts[j])
//           + 2 * (pos_cost - neg_cost)(sigmoid(pred_class[i, tid_j]))
// i in [0, bs*Q=8192), j in [0, bs*T=4096), num_classes = 2.
//
// HBM-write-bound (134 MB out). R4 change: RPB 4 -> 8 to cut VMEM instruction
// issue (3 target loads amortized over 8 row-stores instead of 4):
//   VMEM/iter: 7 per 4 stores -> 11 per 8 stores  (1.75 -> 1.375 per store)
// which moves the VMEM-issue time (~24us) back under the HBM floor (~19.5us).
// Grid 1024 blocks = 4 blocks/CU = 16 waves/CU.

#define ALPHA  0.25f
#define EPS_F  1e-8f
#define CLS_W  2.0f

typedef float f32x4 __attribute__((ext_vector_type(4)));

__device__ __forceinline__ float focal_cc(float x) {
    // p = sigmoid(x); returns CLS_W * (pos_cost - neg_cost), gamma = 2
    float p  = 1.0f / (1.0f + expf(-x));
    float om = 1.0f - p;
    float pos = ALPHA          * om * om * (-logf(p  + EPS_F));
    float neg = (1.0f - ALPHA) * p  * p  * (-logf(om + EPS_F));
    return CLS_W * (pos - neg);
}

template <int RPB>
__global__ __launch_bounds__(256)
void hm_cost_kernel(const float2* __restrict__ pred_class,   // [rows] (2 classes)
                    const float2* __restrict__ pred_pts,     // [rows]
                    const int*    __restrict__ tgt_ids,      // [cols]
                    const float2* __restrict__ tgt_pts,      // [cols]
                    float*        __restrict__ out,          // [rows, cols]
                    int cols) {
    const int row0 = blockIdx.x * RPB;

    // One lane per row computes the per-row scalars; everyone reads from LDS.
    __shared__ float s_px[RPB], s_py[RPB], s_cc0[RPB], s_cc1[RPB];
    if (threadIdx.x < RPB) {
        const int r = threadIdx.x;
        const float2 x  = pred_class[row0 + r];
        const float2 pt = pred_pts[row0 + r];
        s_px[r]  = pt.x;
        s_py[r]  = pt.y;
        s_cc0[r] = focal_cc(x.x);
        s_cc1[r] = focal_cc(x.y);
    }
    __syncthreads();

    float px[RPB], py[RPB], cc0[RPB], cc1[RPB];
#pragma unroll
    for (int r = 0; r < RPB; ++r) {
        px[r] = s_px[r];  py[r] = s_py[r];
        cc0[r] = s_cc0[r]; cc1[r] = s_cc1[r];
    }

    const int cols4 = cols >> 2;                 // float4 granularity
    const float4* tp4 = reinterpret_cast<const float4*>(tgt_pts);
    const int4*   id4 = reinterpret_cast<const int4*>(tgt_ids);
    f32x4* out4 = reinterpret_cast<f32x4*>(out);

    for (int j4 = threadIdx.x; j4 < cols4; j4 += blockDim.x) {
        const float4 tpA = tp4[j4 * 2 + 0];      // tx0, ty0, tx1, ty1
        const float4 tpB = tp4[j4 * 2 + 1];      // tx2, ty2, tx3, ty3
        const int4   id  = id4[j4];

#pragma unroll
        for (int r = 0; r < RPB; ++r) {
            const float qx = px[r], qy = py[r];
            const float c0 = cc0[r], c1 = cc1[r];
            f32x4 o;
            o.x = 10.0f * (fabsf(qx - tpA.x) + fabsf(qy - tpA.y)) + (id.x ? c1 : c0);
            o.y = 10.0f * (fabsf(qx - tpA.z) + fabsf(qy - tpA.w)) + (id.y ? c1 : c0);
            o.z = 10.0f * (fabsf(qx - tpB.x) + fabsf(qy - tpB.y)) + (id.z ? c1 : c0);
            o.w = 10.0f * (fabsf(qx - tpB.z) + fabsf(qy - tpB.w)) + (id.w ? c1 : c0);
            __builtin_nontemporal_store(o, &out4[(size_t)(row0 + r) * cols4 + j4]);
        }
    }
}

extern "C" void kernel_launch(void* const* d_in, const int* in_sizes, int n_in,
                              void* d_out, int out_size, void* d_ws, size_t ws_size,
                              hipStream_t stream) {
    // inputs: pred_class [bs,Q,2] f32, pred_points [bs,Q,2] f32,
    //         gt_class [bs,T] int32, gt_points [bs,T,2] f32
    const float2* pred_class = reinterpret_cast<const float2*>(d_in[0]);
    const float2* pred_pts   = reinterpret_cast<const float2*>(d_in[1]);
    const int*    tgt_ids    = reinterpret_cast<const int*>(d_in[2]);
    const float2* tgt_pts    = reinterpret_cast<const float2*>(d_in[3]);
    float*        out        = reinterpret_cast<float*>(d_out);

    const int rows = in_sizes[1] / 2;   // bs*Q
    const int cols = in_sizes[2];       // bs*T

    constexpr int RPB = 8;
    const int grid = rows / RPB;        // 1024 blocks
    hm_cost_kernel<RPB><<<grid, 256, 0, stream>>>(
        pred_class, pred_pts, tgt_ids, tgt_pts, out, cols);
}

// Round 5
// 27.251 us; speedup vs baseline: 1.0842x; 1.0842x over previous
//
#include <hip/hip_runtime.h>
#include <hip/hip_bf16.h>

// HungarianMatcher cost matrix:
//   C[i, j] = 10 * L1(pred_pts[i], gt_pts[j])
//           + 2 * (pos_cost - neg_cost)(sigmoid(pred_class[i, tid_j]))
// i in [0, bs*Q=8192), j in [0, bs*T=4096), num_classes = 2.
//
// R5: clean A/B vs R3 — drop nontemporal stores, keep RPB=4 + LDS prologue.
// Rationale: output (134 MB) fits in the 256 MB memory-side Infinity Cache;
// cached stores can complete at LLC-ingest BW and drain after kernel end,
// while nt stores bypass the LLC and pin us to direct-HBM write rate.

#define ALPHA  0.25f
#define EPS_F  1e-8f
#define CLS_W  2.0f

typedef float f32x4 __attribute__((ext_vector_type(4)));

__device__ __forceinline__ float focal_cc(float x) {
    // p = sigmoid(x); returns CLS_W * (pos_cost - neg_cost), gamma = 2
    float p  = 1.0f / (1.0f + expf(-x));
    float om = 1.0f - p;
    float pos = ALPHA          * om * om * (-logf(p  + EPS_F));
    float neg = (1.0f - ALPHA) * p  * p  * (-logf(om + EPS_F));
    return CLS_W * (pos - neg);
}

template <int RPB>
__global__ __launch_bounds__(256)
void hm_cost_kernel(const float2* __restrict__ pred_class,   // [rows] (2 classes)
                    const float2* __restrict__ pred_pts,     // [rows]
                    const int*    __restrict__ tgt_ids,      // [cols]
                    const float2* __restrict__ tgt_pts,      // [cols]
                    float*        __restrict__ out,          // [rows, cols]
                    int cols) {
    const int row0 = blockIdx.x * RPB;

    // One lane per row computes the per-row scalars; everyone reads from LDS.
    __shared__ float s_px[RPB], s_py[RPB], s_cc0[RPB], s_cc1[RPB];
    if (threadIdx.x < RPB) {
        const int r = threadIdx.x;
        const float2 x  = pred_class[row0 + r];
        const float2 pt = pred_pts[row0 + r];
        s_px[r]  = pt.x;
        s_py[r]  = pt.y;
        s_cc0[r] = focal_cc(x.x);
        s_cc1[r] = focal_cc(x.y);
    }
    __syncthreads();

    float px[RPB], py[RPB], cc0[RPB], cc1[RPB];
#pragma unroll
    for (int r = 0; r < RPB; ++r) {
        px[r] = s_px[r];  py[r] = s_py[r];
        cc0[r] = s_cc0[r]; cc1[r] = s_cc1[r];
    }

    const int cols4 = cols >> 2;                 // float4 granularity
    const float4* tp4 = reinterpret_cast<const float4*>(tgt_pts);
    const int4*   id4 = reinterpret_cast<const int4*>(tgt_ids);
    f32x4* out4 = reinterpret_cast<f32x4*>(out);

    for (int j4 = threadIdx.x; j4 < cols4; j4 += blockDim.x) {
        const float4 tpA = tp4[j4 * 2 + 0];      // tx0, ty0, tx1, ty1
        const float4 tpB = tp4[j4 * 2 + 1];      // tx2, ty2, tx3, ty3
        const int4   id  = id4[j4];

#pragma unroll
        for (int r = 0; r < RPB; ++r) {
            const float qx = px[r], qy = py[r];
            const float c0 = cc0[r], c1 = cc1[r];
            f32x4 o;
            o.x = 10.0f * (fabsf(qx - tpA.x) + fabsf(qy - tpA.y)) + (id.x ? c1 : c0);
            o.y = 10.0f * (fabsf(qx - tpA.z) + fabsf(qy - tpA.w)) + (id.y ? c1 : c0);
            o.z = 10.0f * (fabsf(qx - tpB.x) + fabsf(qy - tpB.y)) + (id.z ? c1 : c0);
            o.w = 10.0f * (fabsf(qx - tpB.z) + fabsf(qy - tpB.w)) + (id.w ? c1 : c0);
            out4[(size_t)(row0 + r) * cols4 + j4] = o;
        }
    }
}

extern "C" void kernel_launch(void* const* d_in, const int* in_sizes, int n_in,
                              void* d_out, int out_size, void* d_ws, size_t ws_size,
                              hipStream_t stream) {
    // inputs: pred_class [bs,Q,2] f32, pred_points [bs,Q,2] f32,
    //         gt_class [bs,T] int32, gt_points [bs,T,2] f32
    const float2* pred_class = reinterpret_cast<const float2*>(d_in[0]);
    const float2* pred_pts   = reinterpret_cast<const float2*>(d_in[1]);
    const int*    tgt_ids    = reinterpret_cast<const int*>(d_in[2]);
    const float2* tgt_pts    = reinterpret_cast<const float2*>(d_in[3]);
    float*        out        = reinterpret_cast<float*>(d_out);

    const int rows = in_sizes[1] / 2;   // bs*Q
    const int cols = in_sizes[2];       // bs*T

    constexpr int RPB = 4;
    const int grid = rows / RPB;        // 2048 blocks
    hm_cost_kernel<RPB><<<grid, 256, 0, stream>>>(
        pred_class, pred_pts, tgt_ids, tgt_pts, out, cols);
}

// Round 6
// 27.104 us; speedup vs baseline: 1.0901x; 1.0054x over previous
//
#include <hip/hip_runtime.h>
#include <hip/hip_bf16.h>

// HungarianMatcher cost matrix:
//   C[i, j] = 10 * L1(pred_pts[i], gt_pts[j])
//           + 2 * (pos_cost - neg_cost)(sigmoid(pred_class[i, tid_j]))
// i in [0, bs*Q=8192), j in [0, bs*T=4096), num_classes = 2.
//
// R6: test the store-concurrency hypothesis. The rocclr fill kernel reaches
// 6.9 TB/s at ~3 waves/CU with deep sequential streams; we were at 32 waves/CU
// with 128 interleaved row-streams per CU. Grid 2048 -> 512 blocks (2/CU,
// 8 waves/CU); each block owns GROUPS=4 row-groups via an outer loop. All 16
// row-scalars are computed by 16 lanes once at block start (single barrier),
// so the streaming loop has no barriers and minimal VALU.

#define ALPHA  0.25f
#define EPS_F  1e-8f
#define CLS_W  2.0f

typedef float f32x4 __attribute__((ext_vector_type(4)));

__device__ __forceinline__ float focal_cc(float x) {
    // p = sigmoid(x); returns CLS_W * (pos_cost - neg_cost), gamma = 2
    float p  = 1.0f / (1.0f + expf(-x));
    float om = 1.0f - p;
    float pos = ALPHA          * om * om * (-logf(p  + EPS_F));
    float neg = (1.0f - ALPHA) * p  * p  * (-logf(om + EPS_F));
    return CLS_W * (pos - neg);
}

template <int RPB, int GROUPS>
__global__ __launch_bounds__(256)
void hm_cost_kernel(const float2* __restrict__ pred_class,   // [rows] (2 classes)
                    const float2* __restrict__ pred_pts,     // [rows]
                    const int*    __restrict__ tgt_ids,      // [cols]
                    const float2* __restrict__ tgt_pts,      // [cols]
                    float*        __restrict__ out,          // [rows, cols]
                    int cols, int nblocks) {
    // Scalars for all GROUPS*RPB rows this block will touch.
    __shared__ float s_px[GROUPS][RPB], s_py[GROUPS][RPB],
                     s_cc0[GROUPS][RPB], s_cc1[GROUPS][RPB];
    if (threadIdx.x < GROUPS * RPB) {
        const int gg = threadIdx.x / RPB;
        const int rr = threadIdx.x % RPB;
        const int row = (gg * nblocks + blockIdx.x) * RPB + rr;
        const float2 x  = pred_class[row];
        const float2 pt = pred_pts[row];
        s_px[gg][rr]  = pt.x;
        s_py[gg][rr]  = pt.y;
        s_cc0[gg][rr] = focal_cc(x.x);
        s_cc1[gg][rr] = focal_cc(x.y);
    }
    __syncthreads();

    const int cols4 = cols >> 2;                 // float4 granularity
    const float4* tp4 = reinterpret_cast<const float4*>(tgt_pts);
    const int4*   id4 = reinterpret_cast<const int4*>(tgt_ids);
    f32x4* out4 = reinterpret_cast<f32x4*>(out);

    for (int g = 0; g < GROUPS; ++g) {
        const int row0 = (g * nblocks + blockIdx.x) * RPB;

        float px[RPB], py[RPB], cc0[RPB], cc1[RPB];
#pragma unroll
        for (int r = 0; r < RPB; ++r) {
            px[r]  = s_px[g][r];   py[r]  = s_py[g][r];
            cc0[r] = s_cc0[g][r];  cc1[r] = s_cc1[g][r];
        }

        for (int j4 = threadIdx.x; j4 < cols4; j4 += blockDim.x) {
            const float4 tpA = tp4[j4 * 2 + 0];  // tx0, ty0, tx1, ty1
            const float4 tpB = tp4[j4 * 2 + 1];  // tx2, ty2, tx3, ty3
            const int4   id  = id4[j4];

#pragma unroll
            for (int r = 0; r < RPB; ++r) {
                const float qx = px[r], qy = py[r];
                const float c0 = cc0[r], c1 = cc1[r];
                f32x4 o;
                o.x = 10.0f * (fabsf(qx - tpA.x) + fabsf(qy - tpA.y)) + (id.x ? c1 : c0);
                o.y = 10.0f * (fabsf(qx - tpA.z) + fabsf(qy - tpA.w)) + (id.y ? c1 : c0);
                o.z = 10.0f * (fabsf(qx - tpB.x) + fabsf(qy - tpB.y)) + (id.z ? c1 : c0);
                o.w = 10.0f * (fabsf(qx - tpB.z) + fabsf(qy - tpB.w)) + (id.w ? c1 : c0);
                out4[(size_t)(row0 + r) * cols4 + j4] = o;
            }
        }
    }
}

extern "C" void kernel_launch(void* const* d_in, const int* in_sizes, int n_in,
                              void* d_out, int out_size, void* d_ws, size_t ws_size,
                              hipStream_t stream) {
    // inputs: pred_class [bs,Q,2] f32, pred_points [bs,Q,2] f32,
    //         gt_class [bs,T] int32, gt_points [bs,T,2] f32
    const float2* pred_class = reinterpret_cast<const float2*>(d_in[0]);
    const float2* pred_pts   = reinterpret_cast<const float2*>(d_in[1]);
    const int*    tgt_ids    = reinterpret_cast<const int*>(d_in[2]);
    const float2* tgt_pts    = reinterpret_cast<const float2*>(d_in[3]);
    float*        out        = reinterpret_cast<float*>(d_out);

    const int rows = in_sizes[1] / 2;   // bs*Q = 8192
    const int cols = in_sizes[2];       // bs*T = 4096

    constexpr int RPB = 4;
    constexpr int GROUPS = 4;
    const int nblocks = rows / (RPB * GROUPS);   // 512 blocks = 2/CU
    hm_cost_kernel<RPB, GROUPS><<<nblocks, 256, 0, stream>>>(
        pred_class, pred_pts, tgt_ids, tgt_pts, out, cols, nblocks);
}

// Round 7
// 25.955 us; speedup vs baseline: 1.1383x; 1.0443x over previous
//
#include <hip/hip_runtime.h>
#include <hip/hip_bf16.h>

// HungarianMatcher cost matrix:
//   C[i, j] = 10 * L1(pred_pts[i], gt_pts[j])
//           + 2 * (pos_cost - neg_cost)(sigmoid(pred_class[i, tid_j]))
// i in [0, bs*Q=8192), j in [0, bs*T=4096), num_classes = 2.
//
// R7: memset-shaped store stream. Flat grid-stride over the output in float4
// units, TOTAL = 512 blocks x 512 thr = 262144 threads: each iteration the
// whole chip writes ONE contiguous 4 MB window (like the rocclr fill kernel
// that hits 6.9 TB/s), instead of thousands of private 1 KB streams.
// Structure bonus: i*TOTAL % cols4 == 0, so each thread's column is
// loop-invariant (targets loaded ONCE into registers) and the row per iter is
// rbase + row_step*i, thread-uniform (one LDS float4 broadcast per iter).

#define ALPHA  0.25f
#define EPS_F  1e-8f
#define CLS_W  2.0f

typedef float f32x4 __attribute__((ext_vector_type(4)));

__device__ __forceinline__ float focal_cc(float x) {
    // p = sigmoid(x); returns CLS_W * (pos_cost - neg_cost), gamma = 2
    float p  = 1.0f / (1.0f + expf(-x));
    float om = 1.0f - p;
    float pos = ALPHA          * om * om * (-logf(p  + EPS_F));
    float neg = (1.0f - ALPHA) * p  * p  * (-logf(om + EPS_F));
    return CLS_W * (pos - neg);
}

template <int ITERS>
__global__ __launch_bounds__(512)
void hm_cost_kernel(const float2* __restrict__ pred_class,  // [rows] (2 classes)
                    const float2* __restrict__ pred_pts,    // [rows]
                    const int*    __restrict__ tgt_ids,     // [cols]
                    const float2* __restrict__ tgt_pts,     // [cols]
                    float*        __restrict__ out,         // [rows, cols]
                    int cols4,      // cols/4 = 1024
                    int row_step) { // gridDim*blockDim/cols4 = 256
    const int b   = blockIdx.x;
    const int tid = threadIdx.x;
    const int T   = blockDim.x;                  // 512

    // Rows touched by this block: rbase + row_step*i, i in [0, ITERS).
    // (b*T + tid)/cols4 is tid-invariant because b*T % cols4 + T <= cols4.
    const int rbase = (b * T) / cols4;

    // s_row[i] = {px, py, cc0, cc1} for row rbase + row_step*i
    __shared__ float4 s_row[ITERS];
    if (tid < 2 * ITERS) {
        const int i = tid >> 1, c = tid & 1;
        const int r = rbase + i * row_step;
        const float2 x = pred_class[r];
        ((float*)&s_row[i])[2 + c] = focal_cc(c ? x.y : x.x);
        if (c == 0) {
            const float2 pt = pred_pts[r];
            s_row[i].x = pt.x;
            s_row[i].y = pt.y;
        }
    }
    __syncthreads();

    // Loop-invariant target data for this thread's fixed column group.
    const int col4 = (b * T + tid) % cols4;
    const float4* tp4 = reinterpret_cast<const float4*>(tgt_pts);
    const int4*   id4 = reinterpret_cast<const int4*>(tgt_ids);
    const float4 tpA = tp4[col4 * 2 + 0];        // tx0, ty0, tx1, ty1
    const float4 tpB = tp4[col4 * 2 + 1];        // tx2, ty2, tx3, ty3
    const int4   id  = id4[col4];

    f32x4* out4 = reinterpret_cast<f32x4*>(out);
    size_t idx = (size_t)b * T + tid;            // float4 units
    const size_t stride = (size_t)gridDim.x * T; // 262144 float4 = 4 MB

#pragma unroll 4
    for (int i = 0; i < ITERS; ++i) {
        const float4 s = s_row[i];               // LDS broadcast (wave-uniform)
        const float qx = s.x, qy = s.y, c0 = s.z, c1 = s.w;
        f32x4 o;
        o.x = 10.0f * (fabsf(qx - tpA.x) + fabsf(qy - tpA.y)) + (id.x ? c1 : c0);
        o.y = 10.0f * (fabsf(qx - tpA.z) + fabsf(qy - tpA.w)) + (id.y ? c1 : c0);
        o.z = 10.0f * (fabsf(qx - tpB.x) + fabsf(qy - tpB.y)) + (id.z ? c1 : c0);
        o.w = 10.0f * (fabsf(qx - tpB.z) + fabsf(qy - tpB.w)) + (id.w ? c1 : c0);
        out4[idx] = o;
        idx += stride;
    }
}

extern "C" void kernel_launch(void* const* d_in, const int* in_sizes, int n_in,
                              void* d_out, int out_size, void* d_ws, size_t ws_size,
                              hipStream_t stream) {
    // inputs: pred_class [bs,Q,2] f32, pred_points [bs,Q,2] f32,
    //         gt_class [bs,T] int32, gt_points [bs,T,2] f32
    const float2* pred_class = reinterpret_cast<const float2*>(d_in[0]);
    const float2* pred_pts   = reinterpret_cast<const float2*>(d_in[1]);
    const int*    tgt_ids    = reinterpret_cast<const int*>(d_in[2]);
    const float2* tgt_pts    = reinterpret_cast<const float2*>(d_in[3]);
    float*        out        = reinterpret_cast<float*>(d_out);

    const int rows  = in_sizes[1] / 2;   // bs*Q = 8192
    const int cols  = in_sizes[2];       // bs*T = 4096
    const int cols4 = cols / 4;          // 1024

    constexpr int ITERS = 32;
    constexpr int T = 512;
    const int total4 = rows * cols4;                 // 8.39M float4
    const int grid   = total4 / (T * ITERS);         // 512 blocks
    const int row_step = (grid * T) / cols4;         // 256
    hm_cost_kernel<ITERS><<<grid, T, 0, stream>>>(
        pred_class, pred_pts, tgt_ids, tgt_pts, out, cols4, row_step);
}